// Round 10
// baseline (279.718 us; speedup 1.0000x reference)
//
#include <hip/hip_runtime.h>
#include <hip/hip_bf16.h>

#define N_NODES 50000
#define N_EDGES 800000
#define HDIM 128
#define NGRAPH 512
#define NCLS 10
#define BN_EPS 1e-5f
#define MAXDEG 64   // in-deg ~ Poisson(16) over 50k bins; P(any>=64) ~ 1e-14

typedef unsigned int  uint32;
typedef unsigned short ushort16;

// bf16x2 (packed in a uint) -> float2
__device__ inline float2 bf2f(uint32 u) {
    return make_float2(__uint_as_float(u << 16), __uint_as_float(u & 0xffff0000u));
}
// fp32 -> bf16 bits, round-to-nearest-even
__device__ inline ushort16 f2bf(float f) {
    uint32 u = __float_as_uint(f);
    u += 0x7fffu + ((u >> 16) & 1u);
    return (ushort16)(u >> 16);
}
__device__ inline uint32 packbf2(float lo, float hi) {
    return (uint32)f2bf(lo) | ((uint32)f2bf(hi) << 16);
}

// NOTE (r6-r9 post-mortem): every variant with the restructured gather /
// fused-rsqrt / fp16 cluster sits at 11*2^-12 absmax (threshold 11.28*2^-12)
// regardless of storage dtype, GEMM algorithm, or front pattern. This round
// is the r5-benched pipeline VERBATIM (4*2^-12, pass) + ONLY the
// bucket+gemm1 fusion. Do not "simplify" the numerics here.

#define GEMM1_BLOCKS 1563                  // ceil(50000/32)
#define FRONT_GRID (3 * GEMM1_BLOCKS)      // rem0: gemm1, rem1/2: bucket

// ---------------------------------------------------------------------------
// Fused front: rem!=0 blocks run bucket_edges (atomic-bound, VALU-idle),
// rem==0 blocks run gemm1 fp32 (VALU-bound). Bodies verbatim from r5.
// ---------------------------------------------------------------------------
__global__ __launch_bounds__(256) void front(const float* __restrict__ x,
                                             const float* __restrict__ W1,
                                             ushort16* __restrict__ bufA,
                                             const int* __restrict__ src,
                                             const int* __restrict__ dst,
                                             int* __restrict__ deg,
                                             int* __restrict__ epad)
{
    __shared__ float xs[32][36];
    __shared__ float ws[32][128];
    const int tid = threadIdx.x;
    const int grp = blockIdx.x / 3, rem = blockIdx.x % 3;

    if (rem != 0) {
        // ---- bucket_edges (verbatim r5) ----
        int e = (grp * 2 + (rem - 1)) * 256 + tid;
        if (e < N_EDGES) {
            int d   = dst[e];
            int pos = atomicAdd(&deg[d], 1);
            epad[(size_t)d * MAXDEG + pos] = src[e];
        }
        return;
    }

    // ---- gemm1 (verbatim r5 gemm_nk128<float>) ----
    const int row0 = grp * 32;
    const int tx   = tid & 31;
    const int ty   = tid >> 5;

    float acc[4][4];
    #pragma unroll
    for (int i = 0; i < 4; ++i)
        #pragma unroll
        for (int j = 0; j < 4; ++j) acc[i][j] = 0.f;

    const int lr = tid >> 3;
    const int lk = (tid & 7) << 2;
    const int wr = tid >> 5;
    const int wc = (tid & 31) << 2;

    for (int k0 = 0; k0 < 128; k0 += 32) {
        float4 xv = make_float4(0.f, 0.f, 0.f, 0.f);
        int grow = row0 + lr;
        if (grow < N_NODES) xv = *(const float4*)(x + (size_t)grow * HDIM + k0 + lk);
        xs[lr][lk] = xv.x; xs[lr][lk + 1] = xv.y; xs[lr][lk + 2] = xv.z; xs[lr][lk + 3] = xv.w;
        #pragma unroll
        for (int i = 0; i < 4; ++i) {
            int kk = wr + i * 8;
            *(float4*)&ws[kk][wc] = *(const float4*)(W1 + (size_t)(k0 + kk) * HDIM + wc);
        }
        __syncthreads();
        #pragma unroll
        for (int kk = 0; kk < 32; kk += 4) {
            float4 wv[4];
            #pragma unroll
            for (int j = 0; j < 4; ++j) wv[j] = *(const float4*)&ws[kk + j][tx << 2];
            #pragma unroll
            for (int i = 0; i < 4; ++i) {
                float4 xr = *(const float4*)&xs[ty * 4 + i][kk];
                acc[i][0] += xr.x * wv[0].x; acc[i][1] += xr.x * wv[0].y;
                acc[i][2] += xr.x * wv[0].z; acc[i][3] += xr.x * wv[0].w;
                acc[i][0] += xr.y * wv[1].x; acc[i][1] += xr.y * wv[1].y;
                acc[i][2] += xr.y * wv[1].z; acc[i][3] += xr.y * wv[1].w;
                acc[i][0] += xr.z * wv[2].x; acc[i][1] += xr.z * wv[2].y;
                acc[i][2] += xr.z * wv[2].z; acc[i][3] += xr.z * wv[2].w;
                acc[i][0] += xr.w * wv[3].x; acc[i][1] += xr.w * wv[3].y;
                acc[i][2] += xr.w * wv[3].z; acc[i][3] += xr.w * wv[3].w;
            }
        }
        __syncthreads();
    }
    #pragma unroll
    for (int i = 0; i < 4; ++i) {
        int grow = row0 + ty * 4 + i;
        if (grow < N_NODES) {
            uint2 o;
            o.x = packbf2(acc[i][0], acc[i][1]);
            o.y = packbf2(acc[i][2], acc[i][3]);
            *(uint2*)(bufA + (size_t)grow * HDIM + (tx << 2)) = o;
        }
    }
}

// dis[i] = rsqrt(deg[i] + 1)   (+1 = self loop)  -- verbatim r5
__global__ __launch_bounds__(256) void rsqrt_deg(const int* __restrict__ deg_i,
                                                 float* __restrict__ dis, int n)
{
    int i = blockIdx.x * 256 + threadIdx.x;
    if (i < n) dis[i] = rsqrtf((float)deg_i[i] + 1.0f);
}

// ---------------------------------------------------------------------------
// Layer-2 GEMM: fp32 VALU, bf16 input, fp32 W2, bf16 out (verbatim r5).
// ---------------------------------------------------------------------------
__global__ __launch_bounds__(256) void gemm2_nk128(const ushort16* __restrict__ X,
                                                   const float* __restrict__ W,
                                                   ushort16* __restrict__ Y, int nrows)
{
    __shared__ float xs[32][36];
    __shared__ float ws[32][128];
    const int t    = threadIdx.x;
    const int row0 = blockIdx.x * 32;
    const int tx   = t & 31;
    const int ty   = t >> 5;

    float acc[4][4];
    #pragma unroll
    for (int i = 0; i < 4; ++i)
        #pragma unroll
        for (int j = 0; j < 4; ++j) acc[i][j] = 0.f;

    const int lr = t >> 3;
    const int lk = (t & 7) << 2;
    const int wr = t >> 5;
    const int wc = (t & 31) << 2;

    for (int k0 = 0; k0 < 128; k0 += 32) {
        float4 xv = make_float4(0.f, 0.f, 0.f, 0.f);
        int grow = row0 + lr;
        if (grow < nrows) {
            uint2 u = *(const uint2*)(X + (size_t)grow * HDIM + k0 + lk);  // 4 bf16
            float2 a = bf2f(u.x), bb = bf2f(u.y);
            xv = make_float4(a.x, a.y, bb.x, bb.y);
        }
        xs[lr][lk] = xv.x; xs[lr][lk + 1] = xv.y; xs[lr][lk + 2] = xv.z; xs[lr][lk + 3] = xv.w;
        #pragma unroll
        for (int i = 0; i < 4; ++i) {
            int kk = wr + i * 8;
            *(float4*)&ws[kk][wc] = *(const float4*)(W + (size_t)(k0 + kk) * HDIM + wc);
        }
        __syncthreads();
        #pragma unroll
        for (int kk = 0; kk < 32; kk += 4) {
            float4 wv[4];
            #pragma unroll
            for (int j = 0; j < 4; ++j) wv[j] = *(const float4*)&ws[kk + j][tx << 2];
            #pragma unroll
            for (int i = 0; i < 4; ++i) {
                float4 xr = *(const float4*)&xs[ty * 4 + i][kk];
                acc[i][0] += xr.x * wv[0].x; acc[i][1] += xr.x * wv[0].y;
                acc[i][2] += xr.x * wv[0].z; acc[i][3] += xr.x * wv[0].w;
                acc[i][0] += xr.y * wv[1].x; acc[i][1] += xr.y * wv[1].y;
                acc[i][2] += xr.y * wv[1].z; acc[i][3] += xr.y * wv[1].w;
                acc[i][0] += xr.z * wv[2].x; acc[i][1] += xr.z * wv[2].y;
                acc[i][2] += xr.z * wv[2].z; acc[i][3] += xr.z * wv[2].w;
                acc[i][0] += xr.w * wv[3].x; acc[i][1] += xr.w * wv[3].y;
                acc[i][2] += xr.w * wv[3].z; acc[i][3] += xr.w * wv[3].w;
            }
        }
        __syncthreads();
    }
    #pragma unroll
    for (int i = 0; i < 4; ++i) {
        int grow = row0 + ty * 4 + i;
        if (grow < nrows) {
            uint2 o;
            o.x = packbf2(acc[i][0], acc[i][1]);
            o.y = packbf2(acc[i][2], acc[i][3]);
            *(uint2*)(Y + (size_t)grow * HDIM + (tx << 2)) = o;
        }
    }
}

// ---------------------------------------------------------------------------
// Gather + self-loop + bias + BN + ReLU (verbatim r5 body: dis[] table,
// int epad, quarter-wave per edge, no unroll).
// ---------------------------------------------------------------------------
__global__ __launch_bounds__(256) void gather_bn_relu(const ushort16* __restrict__ h,
                                                      const int* __restrict__ epad,
                                                      const int* __restrict__ deg,
                                                      const float* __restrict__ dis,
                                                      const float* __restrict__ b,
                                                      const float* __restrict__ gamma,
                                                      const float* __restrict__ beta,
                                                      const float* __restrict__ mean,
                                                      const float* __restrict__ var,
                                                      ushort16* __restrict__ out, int n)
{
    int node = blockIdx.x * 4 + (threadIdx.x >> 6);
    int lane = threadIdx.x & 63;
    if (node >= n) return;
    const int q    = lane >> 4;          // quarter: which edge of the 4
    const int ci   = (lane & 15) << 3;   // 8 channels per lane
    const int cnt_e = deg[node];
    const int base  = node * MAXDEG;
    const float dd  = dis[node];

    // preload this node's edge list: lane l owns edge l (cnt_e <= 64)
    int   s_all  = 0;
    float nm_all = 0.f;
    if (lane < cnt_e) {
        s_all  = epad[base + lane];
        nm_all = dis[s_all] * dd;
    }

    float acc[8] = {0.f, 0.f, 0.f, 0.f, 0.f, 0.f, 0.f, 0.f};
    for (int j = q; j < cnt_e; j += 4) {
        int   s  = __shfl(s_all, j);
        float nm = __shfl(nm_all, j);
        uint4 v  = *(const uint4*)(h + (size_t)s * HDIM + ci);
        float2 f0 = bf2f(v.x), f1 = bf2f(v.y), f2 = bf2f(v.z), f3 = bf2f(v.w);
        acc[0] += f0.x * nm; acc[1] += f0.y * nm;
        acc[2] += f1.x * nm; acc[3] += f1.y * nm;
        acc[4] += f2.x * nm; acc[5] += f2.y * nm;
        acc[6] += f3.x * nm; acc[7] += f3.y * nm;
    }
    #pragma unroll
    for (int k = 0; k < 8; ++k) {
        acc[k] += __shfl_xor(acc[k], 16);
        acc[k] += __shfl_xor(acc[k], 32);
    }

    if (q == 0) {
        uint4 hv = *(const uint4*)(h + (size_t)node * HDIM + ci);
        float2 g0 = bf2f(hv.x), g1 = bf2f(hv.y), g2 = bf2f(hv.z), g3 = bf2f(hv.w);
        float a[8] = {acc[0] + g0.x * dd * dd, acc[1] + g0.y * dd * dd,
                      acc[2] + g1.x * dd * dd, acc[3] + g1.y * dd * dd,
                      acc[4] + g2.x * dd * dd, acc[5] + g2.y * dd * dd,
                      acc[6] + g3.x * dd * dd, acc[7] + g3.y * dd * dd};
        float o[8];
        #pragma unroll
        for (int k = 0; k < 8; ++k) {
            int c = ci + k;
            float sc = gamma[c] * rsqrtf(var[c] + BN_EPS);
            float r  = (a[k] + b[c] - mean[c]) * sc + beta[c];
            o[k] = fmaxf(r, 0.f);
        }
        uint4 ov;
        ov.x = packbf2(o[0], o[1]); ov.y = packbf2(o[2], o[3]);
        ov.z = packbf2(o[4], o[5]); ov.w = packbf2(o[6], o[7]);
        *(uint4*)(out + (size_t)node * HDIM + ci) = ov;
    }
}

// ---------------------------------------------------------------------------
// Pool (verbatim r5): sums[batch[n]][c] += h[n][c]; batch sorted.
// ---------------------------------------------------------------------------
__global__ __launch_bounds__(128) void pool_sum(const ushort16* __restrict__ h,
                                                const int* __restrict__ batch,
                                                float* __restrict__ sums,
                                                float* __restrict__ cnt, int n)
{
    int c  = threadIdx.x;
    int n0 = blockIdx.x * 32;
    if (n0 >= n) return;
    int nend = min(n0 + 32, n);
    int curg = batch[n0];
    float acc = 0.f;
    int run = 0;
    for (int i = n0; i < nend; ++i) {
        int g   = batch[i];
        float v = __uint_as_float((uint32)h[(size_t)i * HDIM + c] << 16);
        if (g != curg) {
            atomicAdd(&sums[(size_t)curg * HDIM + c], acc);
            if (c == 0) atomicAdd(&cnt[curg], (float)run);
            acc = 0.f; run = 0; curg = g;
        }
        acc += v; run++;
    }
    atomicAdd(&sums[(size_t)curg * HDIM + c], acc);
    if (c == 0) atomicAdd(&cnt[curg], (float)run);
}

// ---------------------------------------------------------------------------
// out[g][c] = (sums[g]/max(cnt[g],1)) . Wlin[:,c] + blin[c]  (verbatim r5)
// ---------------------------------------------------------------------------
__global__ __launch_bounds__(128) void final_lin(const float* __restrict__ sums,
                                                 const float* __restrict__ cnt,
                                                 const float* __restrict__ Wlin,
                                                 const float* __restrict__ blin,
                                                 float* __restrict__ out)
{
    __shared__ float red[NCLS][2];
    int g = blockIdx.x;
    int t = threadIdx.x;
    float ic = 1.f / fmaxf(cnt[g], 1.f);
    float v  = sums[(size_t)g * HDIM + t] * ic;
    float p[NCLS];
    #pragma unroll
    for (int c = 0; c < NCLS; ++c) p[c] = v * Wlin[t * NCLS + c];
    #pragma unroll
    for (int c = 0; c < NCLS; ++c) {
        float x = p[c];
        for (int off = 32; off > 0; off >>= 1) x += __shfl_down(x, off);
        if ((t & 63) == 0) red[c][t >> 6] = x;
    }
    __syncthreads();
    if (t < NCLS) out[g * NCLS + t] = red[t][0] + red[t][1] + blin[t];
}

// ---------------------------------------------------------------------------
extern "C" void kernel_launch(void* const* d_in, const int* in_sizes, int n_in,
                              void* d_out, int out_size, void* d_ws, size_t ws_size,
                              hipStream_t stream)
{
    const float* x     = (const float*)d_in[0];
    const int*   ei    = (const int*)d_in[1];
    const int*   srcp  = ei;
    const int*   dstp  = ei + N_EDGES;
    const int*   batch = (const int*)d_in[2];
    const float* W1    = (const float*)d_in[3];
    const float* b1    = (const float*)d_in[4];
    const float* g1    = (const float*)d_in[5];
    const float* be1   = (const float*)d_in[6];
    const float* m1    = (const float*)d_in[7];
    const float* v1    = (const float*)d_in[8];
    const float* W2    = (const float*)d_in[9];
    const float* b2    = (const float*)d_in[10];
    const float* g2    = (const float*)d_in[11];
    const float* be2   = (const float*)d_in[12];
    const float* m2    = (const float*)d_in[13];
    const float* v2    = (const float*)d_in[14];
    const float* Wlin  = (const float*)d_in[15];
    const float* blin  = (const float*)d_in[16];
    float*       out   = (float*)d_out;

    // workspace layout (verbatim r5, ~39 MiB):
    // bufA(bf16) | bufB(bf16) | epad(int) | deg | cnt | sums | dis
    ushort16* bufA = (ushort16*)d_ws;
    ushort16* bufB = bufA + (size_t)N_NODES * HDIM;
    int*   epad = (int*)(bufB + (size_t)N_NODES * HDIM);
    int*   deg  = epad + (size_t)N_NODES * MAXDEG;
    float* cnt  = (float*)(deg + N_NODES);
    float* sums = cnt + NGRAPH;
    float* dis  = sums + (size_t)NGRAPH * HDIM;

    // zero deg | cnt | sums in one contiguous memset
    hipMemsetAsync(deg, 0,
                   (N_NODES + NGRAPH + (size_t)NGRAPH * HDIM) * sizeof(float), stream);

    // ---- fused front: bucket (atomic-bound) + gemm1 fp32 (VALU-bound) ----
    front<<<FRONT_GRID, 256, 0, stream>>>(x, W1, bufA, srcp, dstp, deg, epad);
    rsqrt_deg<<<(N_NODES + 255) / 256, 256, 0, stream>>>(deg, dis, N_NODES);

    const int gather_blocks = (N_NODES + 3) / 4;

    // ---- layer 1 aggregation ----
    gather_bn_relu<<<gather_blocks, 256, 0, stream>>>(bufA, epad, deg, dis,
                                                      b1, g1, be1, m1, v1, bufB, N_NODES);
    // ---- layer 2 ----
    gemm2_nk128<<<(N_NODES + 31) / 32, 256, 0, stream>>>(bufB, W2, bufA, N_NODES);
    gather_bn_relu<<<gather_blocks, 256, 0, stream>>>(bufA, epad, deg, dis,
                                                      b2, g2, be2, m2, v2, bufB, N_NODES);
    // ---- pool + head ----
    pool_sum<<<(N_NODES + 31) / 32, 128, 0, stream>>>(bufB, batch, sums, cnt, N_NODES);
    final_lin<<<NGRAPH, 128, 0, stream>>>(sums, cnt, Wlin, blin, out);
}